// Round 2
// baseline (2813.674 us; speedup 1.0000x reference)
//
#include <hip/hip_runtime.h>
#include <hip/hip_bf16.h>
#include <math.h>

#define N_TOKENS 16384
#define D_MODEL  4096
#define N_EXP    64

#define TOK_BLK  64     // tokens per block
#define BK       64     // d-depth per LDS stage
#define E_CHUNK  16     // experts per wave (4 waves x 16 = 64)

// ---------------------------------------------------------------------------
// GEMM: block = 256 threads = 4 waves. Block covers 64 tokens x all 64
// experts x a D-slice. Wave w handles experts [16w, 16w+16).
// x staged into LDS transposed (xs[d][token], row pad +1) so:
//   - global loads are perfectly coalesced (wave = 4 x 256B rows)
//   - compute reads xs[dd][lane] are 2-way bank aliases (free)
// w is read with wave-uniform addresses -> scalar loads, FMA uses SGPR src.
// ---------------------------------------------------------------------------
__global__ void __launch_bounds__(256, 8)
router_gemm2(const float* __restrict__ x, const float* __restrict__ w,
             float* __restrict__ partial, int dlen) {
    __shared__ float xs[BK][TOK_BLK + 1];   // ~16.25 KB

    int tid  = threadIdx.x;
    int wave = tid >> 6;
    int lane = tid & 63;
    int tok0 = blockIdx.x * TOK_BLK;
    int d0   = blockIdx.y * dlen;
    int e0   = wave * E_CHUNK;

    float acc[E_CHUNK];
#pragma unroll
    for (int j = 0; j < E_CHUNK; ++j) acc[j] = 0.f;

    // staging decomposition: thread (r = tid>>4, c = (tid&15)*4) loads
    // tokens {r, r+16, r+32, r+48}, cols [c, c+4)
    int r = tid >> 4;
    int c = (tid & 15) * 4;

    for (int k = 0; k < dlen; k += BK) {
        __syncthreads();
        {
            const float* src = x + (size_t)tok0 * D_MODEL + d0 + k;
#pragma unroll
            for (int p = 0; p < 4; ++p) {
                int t = r + p * 16;
                float4 v = *(const float4*)(src + (size_t)t * D_MODEL + c);
                xs[c + 0][t] = v.x;
                xs[c + 1][t] = v.y;
                xs[c + 2][t] = v.z;
                xs[c + 3][t] = v.w;
            }
        }
        __syncthreads();

        const float* wp = w + d0 + k;   // row e: wp + e*D_MODEL
#pragma unroll 2
        for (int dd = 0; dd < BK; dd += 4) {
            float x0 = xs[dd + 0][lane];
            float x1 = xs[dd + 1][lane];
            float x2 = xs[dd + 2][lane];
            float x3 = xs[dd + 3][lane];
#pragma unroll
            for (int j = 0; j < E_CHUNK; ++j) {
                const float* wr = wp + (size_t)(e0 + j) * D_MODEL + dd;
                float a = acc[j];
                a = fmaf(x0, wr[0], a);
                a = fmaf(x1, wr[1], a);
                a = fmaf(x2, wr[2], a);
                a = fmaf(x3, wr[3], a);
                acc[j] = a;
            }
        }
    }

    // partial[slice][token][e0 .. e0+16)
    float* po = partial + (size_t)blockIdx.y * N_TOKENS * N_EXP
                        + (size_t)(tok0 + lane) * N_EXP + e0;
#pragma unroll
    for (int j = 0; j < E_CHUNK; j += 4)
        *(float4*)(po + j) = make_float4(acc[j], acc[j+1], acc[j+2], acc[j+3]);
}

// ---------------------------------------------------------------------------
// Phase B: reduce slices -> logits, softmax, top-2 (on logits; softmax is
// monotonic), outputs, p_i/f_i accumulation. One wave per token per iter.
// grid = 2048 blocks x 8 tokens/block.
// ---------------------------------------------------------------------------
__global__ void __launch_bounds__(256)
router_phaseB(const float* __restrict__ partial, int n_slices,
              float* __restrict__ out,
              float* __restrict__ p_sum, float* __restrict__ f_sum) {
    __shared__ float p_acc[4][N_EXP];
    __shared__ float f_acc[4][N_EXP];

    int tid = threadIdx.x;
    int wave = tid >> 6;
    int lane = tid & 63;

    p_acc[wave][lane] = 0.f;
    f_acc[wave][lane] = 0.f;

    for (int it = 0; it < 2; ++it) {
        int token = blockIdx.x * 8 + it * 4 + wave;

        float logit = 0.f;
        size_t base = (size_t)token * N_EXP + lane;
        for (int s = 0; s < n_slices; ++s)
            logit += partial[(size_t)s * N_TOKENS * N_EXP + base];

        // chain 1: fused max + argmax (ties -> lower index, per jax.lax.top_k)
        float m = logit; int i1 = lane;
#pragma unroll
        for (int off = 1; off < 64; off <<= 1) {
            float ov = __shfl_xor(m, off, 64);
            int   oi = __shfl_xor(i1, off, 64);
            if (ov > m || (ov == m && oi < i1)) { m = ov; i1 = oi; }
        }

        // chain 2: softmax denom
        float p = expf(logit - m);
        float denom = p;
#pragma unroll
        for (int off = 1; off < 64; off <<= 1)
            denom += __shfl_xor(denom, off, 64);

        p_acc[wave][lane] += p / denom;

        // chain 3: 2nd max + argmax (exclude i1)
        float l2 = (lane == i1) ? -__builtin_inff() : logit;
        int i2 = lane;
#pragma unroll
        for (int off = 1; off < 64; off <<= 1) {
            float ov = __shfl_xor(l2, off, 64);
            int   oi = __shfl_xor(i2, off, 64);
            if (ov > l2 || (ov == l2 && oi < i2)) { l2 = ov; i2 = oi; }
        }

        if (lane == i1) f_acc[wave][lane] += 1.f;

        if (lane == 0) {
            float p1 = 1.0f / denom;            // exp(m - m) / denom
            float p2 = expf(l2 - m) / denom;
            float s12 = p1 + p2;
            ((float2*)out)[token] = make_float2(p1 / s12, p2 / s12);
            ((float2*)(out + 2 * N_TOKENS))[token] =
                make_float2((float)i1, (float)i2);
        }
    }

    __syncthreads();
    if (tid < N_EXP) {
        float ps = p_acc[0][tid] + p_acc[1][tid] + p_acc[2][tid] + p_acc[3][tid];
        float fs = f_acc[0][tid] + f_acc[1][tid] + f_acc[2][tid] + f_acc[3][tid];
        atomicAdd(&p_sum[tid], ps);
        atomicAdd(&f_sum[tid], fs);
    }
}

// ---------------------------------------------------------------------------
// loss = 0.01 * sum_e (f_e/N) * (p_e/N)
// ---------------------------------------------------------------------------
__global__ void router_loss(const float* __restrict__ p_sum,
                            const float* __restrict__ f_sum,
                            float* __restrict__ out) {
    int lane = threadIdx.x;
    float v = f_sum[lane] * p_sum[lane];
#pragma unroll
    for (int off = 1; off < 64; off <<= 1)
        v += __shfl_xor(v, off, 64);
    if (lane == 0)
        out[4 * N_TOKENS] = 0.01f * v / ((float)N_TOKENS * (float)N_TOKENS);
}

// ---------------------------------------------------------------------------
extern "C" void kernel_launch(void* const* d_in, const int* in_sizes, int n_in,
                              void* d_out, int out_size, void* d_ws, size_t ws_size,
                              hipStream_t stream) {
    const float* x = (const float*)d_in[0];
    const float* w = (const float*)d_in[1];
    float* out = (float*)d_out;
    char* ws = (char*)d_ws;

    const size_t SUM_BYTES = 2 * N_EXP * sizeof(float);

    // largest d-split whose partial buffer fits the workspace
    int n_slices = 1;
    for (int c = 8; c >= 1; c >>= 1) {
        size_t need = (size_t)c * N_TOKENS * N_EXP * sizeof(float)
                      + SUM_BYTES + 512;
        if (need <= ws_size) { n_slices = c; break; }
    }

    size_t partial_bytes = (size_t)n_slices * N_TOKENS * N_EXP * sizeof(float);
    float* partial = (float*)ws;
    float* p_sum = (float*)(ws + partial_bytes);
    float* f_sum = p_sum + N_EXP;

    hipMemsetAsync(p_sum, 0, SUM_BYTES, stream);

    dim3 gridA(N_TOKENS / TOK_BLK, n_slices);
    router_gemm2<<<gridA, 256, 0, stream>>>(x, w, partial, D_MODEL / n_slices);

    router_phaseB<<<N_TOKENS / 8, 256, 0, stream>>>(partial, n_slices, out,
                                                    p_sum, f_sum);

    router_loss<<<1, 64, 0, stream>>>(p_sum, f_sum, out);
}

// Round 3
// 449.445 us; speedup vs baseline: 6.2603x; 6.2603x over previous
//
#include <hip/hip_runtime.h>
#include <hip/hip_bf16.h>
#include <math.h>

#define N_TOKENS 16384
#define D_MODEL  4096
#define N_EXP    64

#define BK     16            // k-depth per LDS tile
#define XS_LD  260           // 256 tokens + 4 pad (keeps 16B align, breaks bank stride)
#define WS_LD  68            // 64 experts + 4 pad
#define PB_BLOCKS 512        // phaseB grid

// ---------------------------------------------------------------------------
// GEMM: block = 256 threads = 4 waves, tile = 256 tokens x 64 experts x kslice.
// Thread register-blocks 8 tokens x 8 experts (acc[8][8] -> 64 VGPRs).
// Wave layout: tg = lane&7 (token group), eg = lane>>3 (expert group);
// wave covers tokens [wave*64, wave*64+64) x all 64 experts.
// Per k-step: 2 ds_read_b128 (x) + 2 ds_read_b128 (w) -> 64 v_fmac_f32.
// 8-lane broadcast on both reads => LDS BW trivial; pads make stores 2-way.
// ---------------------------------------------------------------------------
__global__ void __launch_bounds__(256)
router_gemm3(const float* __restrict__ x, const float* __restrict__ w,
             float* __restrict__ partial, int kslice) {
    __shared__ float xs[BK * XS_LD];   // 16.25 KB
    __shared__ float ws[BK * WS_LD];   //  4.25 KB

    int tid  = threadIdx.x;
    int tok0 = blockIdx.x * 256;
    int k0   = blockIdx.y * kslice;

    int wave = tid >> 6;
    int lane = tid & 63;
    int trow = wave * 64 + (lane & 7) * 8;   // first of this thread's 8 tokens
    int ecol = (lane >> 3) * 8;              // first of this thread's 8 experts

    // staging decomposition: thread covers row s_sub (+p*64 for x), k-chunk s_kc
    int s_sub = tid >> 2;          // 0..63
    int s_kc  = (tid & 3) * 4;     // 0,4,8,12

    float acc[8][8];
#pragma unroll
    for (int t = 0; t < 8; ++t)
#pragma unroll
        for (int e = 0; e < 8; ++e) acc[t][e] = 0.f;

    for (int kk = 0; kk < kslice; kk += BK) {
        // global loads first (no LDS dependency), then barrier, then store
        const float* xsrc = x + (size_t)tok0 * D_MODEL + k0 + kk;
        const float* wsrc = w + k0 + kk;
        float4 xv0 = *(const float4*)(xsrc + (size_t)(s_sub +   0) * D_MODEL + s_kc);
        float4 xv1 = *(const float4*)(xsrc + (size_t)(s_sub +  64) * D_MODEL + s_kc);
        float4 xv2 = *(const float4*)(xsrc + (size_t)(s_sub + 128) * D_MODEL + s_kc);
        float4 xv3 = *(const float4*)(xsrc + (size_t)(s_sub + 192) * D_MODEL + s_kc);
        float4 wv  = *(const float4*)(wsrc + (size_t)s_sub * D_MODEL + s_kc);

        __syncthreads();   // previous tile's reads done

        xs[(s_kc + 0) * XS_LD + s_sub +   0] = xv0.x;
        xs[(s_kc + 1) * XS_LD + s_sub +   0] = xv0.y;
        xs[(s_kc + 2) * XS_LD + s_sub +   0] = xv0.z;
        xs[(s_kc + 3) * XS_LD + s_sub +   0] = xv0.w;
        xs[(s_kc + 0) * XS_LD + s_sub +  64] = xv1.x;
        xs[(s_kc + 1) * XS_LD + s_sub +  64] = xv1.y;
        xs[(s_kc + 2) * XS_LD + s_sub +  64] = xv1.z;
        xs[(s_kc + 3) * XS_LD + s_sub +  64] = xv1.w;
        xs[(s_kc + 0) * XS_LD + s_sub + 128] = xv2.x;
        xs[(s_kc + 1) * XS_LD + s_sub + 128] = xv2.y;
        xs[(s_kc + 2) * XS_LD + s_sub + 128] = xv2.z;
        xs[(s_kc + 3) * XS_LD + s_sub + 128] = xv2.w;
        xs[(s_kc + 0) * XS_LD + s_sub + 192] = xv3.x;
        xs[(s_kc + 1) * XS_LD + s_sub + 192] = xv3.y;
        xs[(s_kc + 2) * XS_LD + s_sub + 192] = xv3.z;
        xs[(s_kc + 3) * XS_LD + s_sub + 192] = xv3.w;
        ws[(s_kc + 0) * WS_LD + s_sub] = wv.x;
        ws[(s_kc + 1) * WS_LD + s_sub] = wv.y;
        ws[(s_kc + 2) * WS_LD + s_sub] = wv.z;
        ws[(s_kc + 3) * WS_LD + s_sub] = wv.w;

        __syncthreads();

#pragma unroll 4
        for (int k = 0; k < BK; ++k) {
            const float* xr = &xs[k * XS_LD + trow];
            const float* wr = &ws[k * WS_LD + ecol];
            float4 xa = *(const float4*)(xr);
            float4 xb = *(const float4*)(xr + 4);
            float4 wa = *(const float4*)(wr);
            float4 wb = *(const float4*)(wr + 4);
            float xf[8] = {xa.x, xa.y, xa.z, xa.w, xb.x, xb.y, xb.z, xb.w};
            float wf[8] = {wa.x, wa.y, wa.z, wa.w, wb.x, wb.y, wb.z, wb.w};
#pragma unroll
            for (int t = 0; t < 8; ++t)
#pragma unroll
                for (int e = 0; e < 8; ++e)
                    acc[t][e] = fmaf(xf[t], wf[e], acc[t][e]);
        }
    }

    // write partial[slice][token][expert]
    float* po = partial + (size_t)blockIdx.y * (N_TOKENS * N_EXP)
                        + (size_t)(tok0 + trow) * N_EXP + ecol;
#pragma unroll
    for (int t = 0; t < 8; ++t) {
        *(float4*)(po + (size_t)t * N_EXP)     =
            make_float4(acc[t][0], acc[t][1], acc[t][2], acc[t][3]);
        *(float4*)(po + (size_t)t * N_EXP + 4) =
            make_float4(acc[t][4], acc[t][5], acc[t][6], acc[t][7]);
    }
}

// ---------------------------------------------------------------------------
// Phase B: reduce k-slices -> logits, softmax, top-2 (on logits; monotonic),
// write outputs + per-block p/f sums (NO atomics).
// grid = PB_BLOCKS, 32 tokens/block (8 iters x 4 waves), lane = expert.
// ---------------------------------------------------------------------------
__global__ void __launch_bounds__(256)
router_phaseB(const float* __restrict__ partial, int n_slices,
              float* __restrict__ out, float* __restrict__ block_sums) {
    __shared__ float p_acc[4][N_EXP];
    __shared__ float f_acc[4][N_EXP];

    int tid  = threadIdx.x;
    int wave = tid >> 6;
    int lane = tid & 63;

    p_acc[wave][lane] = 0.f;
    f_acc[wave][lane] = 0.f;

    for (int it = 0; it < 8; ++it) {
        int token = blockIdx.x * 32 + it * 4 + wave;

        float logit = 0.f;
        size_t base = (size_t)token * N_EXP + lane;
        for (int s = 0; s < n_slices; ++s)
            logit += partial[(size_t)s * (N_TOKENS * N_EXP) + base];

        // max + argmax (ties -> lower index, matching jax.lax.top_k)
        float m = logit; int i1 = lane;
#pragma unroll
        for (int off = 1; off < 64; off <<= 1) {
            float ov = __shfl_xor(m, off, 64);
            int   oi = __shfl_xor(i1, off, 64);
            if (ov > m || (ov == m && oi < i1)) { m = ov; i1 = oi; }
        }

        float p = expf(logit - m);
        float denom = p;
#pragma unroll
        for (int off = 1; off < 64; off <<= 1)
            denom += __shfl_xor(denom, off, 64);

        p_acc[wave][lane] += p / denom;

        // 2nd max + argmax, excluding i1
        float l2 = (lane == i1) ? -__builtin_inff() : logit;
        int i2 = lane;
#pragma unroll
        for (int off = 1; off < 64; off <<= 1) {
            float ov = __shfl_xor(l2, off, 64);
            int   oi = __shfl_xor(i2, off, 64);
            if (ov > l2 || (ov == l2 && oi < i2)) { l2 = ov; i2 = oi; }
        }

        if (lane == i1) f_acc[wave][lane] += 1.f;

        if (lane == 0) {
            float p1 = 1.0f / denom;           // exp(m-m)/denom
            float p2 = expf(l2 - m) / denom;
            float s12 = p1 + p2;
            ((float2*)out)[token] = make_float2(p1 / s12, p2 / s12);
            ((float2*)(out + 2 * N_TOKENS))[token] =
                make_float2((float)i1, (float)i2);
        }
    }

    __syncthreads();
    if (tid < N_EXP) {
        float ps = p_acc[0][tid] + p_acc[1][tid] + p_acc[2][tid] + p_acc[3][tid];
        float fs = f_acc[0][tid] + f_acc[1][tid] + f_acc[2][tid] + f_acc[3][tid];
        block_sums[(size_t)blockIdx.x * 128 + tid]      = ps;
        block_sums[(size_t)blockIdx.x * 128 + 64 + tid] = fs;
    }
}

// ---------------------------------------------------------------------------
// Final: reduce block_sums, loss = 0.01 * sum_e (f_e/N)*(p_e/N).
// 1 block, 256 threads; wave h handles blocks [h*128, h*128+128).
// ---------------------------------------------------------------------------
__global__ void __launch_bounds__(256)
router_final(const float* __restrict__ block_sums, float* __restrict__ out) {
    __shared__ float sp[4][N_EXP];
    __shared__ float sf[4][N_EXP];

    int tid  = threadIdx.x;
    int wave = tid >> 6;
    int lane = tid & 63;

    float ps = 0.f, fs = 0.f;
    for (int b = wave * (PB_BLOCKS / 4); b < (wave + 1) * (PB_BLOCKS / 4); ++b) {
        ps += block_sums[(size_t)b * 128 + lane];
        fs += block_sums[(size_t)b * 128 + 64 + lane];
    }
    sp[wave][lane] = ps;
    sf[wave][lane] = fs;
    __syncthreads();

    if (tid < N_EXP) {
        float pt = sp[0][tid] + sp[1][tid] + sp[2][tid] + sp[3][tid];
        float ft = sf[0][tid] + sf[1][tid] + sf[2][tid] + sf[3][tid];
        float v = pt * ft;
#pragma unroll
        for (int off = 1; off < 64; off <<= 1)
            v += __shfl_xor(v, off, 64);
        if (tid == 0)
            out[4 * N_TOKENS] = 0.01f * v / ((float)N_TOKENS * (float)N_TOKENS);
    }
}

// ---------------------------------------------------------------------------
extern "C" void kernel_launch(void* const* d_in, const int* in_sizes, int n_in,
                              void* d_out, int out_size, void* d_ws, size_t ws_size,
                              hipStream_t stream) {
    const float* x = (const float*)d_in[0];
    const float* w = (const float*)d_in[1];
    float* out = (float*)d_out;
    char* ws = (char*)d_ws;

    const size_t BS_BYTES = (size_t)PB_BLOCKS * 128 * sizeof(float);  // 256 KB

    // largest k-split whose partial buffer fits the workspace
    int ksplit = 1;
    for (int c = 16; c >= 1; c >>= 1) {
        size_t need = (size_t)c * N_TOKENS * N_EXP * sizeof(float) + BS_BYTES + 512;
        if (need <= ws_size) { ksplit = c; break; }
    }

    size_t partial_bytes = (size_t)ksplit * N_TOKENS * N_EXP * sizeof(float);
    float* partial = (float*)ws;
    float* block_sums = (float*)(ws + partial_bytes);

    dim3 gridA(N_TOKENS / 256, ksplit);
    router_gemm3<<<gridA, 256, 0, stream>>>(x, w, partial, D_MODEL / ksplit);

    router_phaseB<<<PB_BLOCKS, 256, 0, stream>>>(partial, ksplit, out, block_sums);

    router_final<<<1, 256, 0, stream>>>(block_sums, out);
}